// Round 3
// baseline (587.574 us; speedup 1.0000x reference)
//
#include <hip/hip_runtime.h>
#include <hip/hip_bf16.h>
#include <cstdint>
#include <math.h>

#define NDIM 1024
#define BDIM 32
#define DDIM 64
#define NEDGE 5

struct Keys { uint32_t a[NEDGE]; uint32_t b[NEDGE]; };

// JAX Threefry-2x32, 20 rounds. Matches jax/_src/prng.py exactly.
#define TF_R(r) do { x0 += x1; x1 = (x1 << (r)) | (x1 >> (32 - (r))); x1 ^= x0; } while (0)
__host__ __device__ inline void tf2x32(uint32_t k0, uint32_t k1,
                                       uint32_t x0, uint32_t x1,
                                       uint32_t& o0, uint32_t& o1) {
  const uint32_t ks2 = k0 ^ k1 ^ 0x1BD11BDAu;
  x0 += k0; x1 += k1;
  TF_R(13); TF_R(15); TF_R(26); TF_R(6);
  x0 += k1; x1 += ks2 + 1u;
  TF_R(17); TF_R(29); TF_R(16); TF_R(24);
  x0 += ks2; x1 += k0 + 2u;
  TF_R(13); TF_R(15); TF_R(26); TF_R(6);
  x0 += k0; x1 += k1 + 3u;
  TF_R(17); TF_R(29); TF_R(16); TF_R(24);
  x0 += k1; x1 += ks2 + 4u;
  TF_R(13); TF_R(15); TF_R(26); TF_R(6);
  x0 += ks2; x1 += k0 + 5u;
  o0 = x0; o1 = x1;
}

// Partitionable threefry bits for linear position p: o0^o1 of tf(key; 0, p).
__device__ __forceinline__ uint32_t tf_bits(uint32_t k0, uint32_t k1, uint32_t p) {
  uint32_t o0, o1;
  tf2x32(k0, k1, 0u, p, o0, o1);
  return o0 ^ o1;
}

// bits -> uniform(1e-10,1) -> gumbel, replicating JAX's exact f32 op sequence
// (separate mul/add rounding — no FMA contraction), double-precision logs.
__device__ __forceinline__ float gumbel_bits(uint32_t bits) {
  float f = __uint_as_float((bits >> 9) | 0x3F800000u) - 1.0f;
  float u = fmaxf(1e-10f, __fadd_rn(__fmul_rn(f, 1.0f - 1e-10f), 1e-10f));
  float t = -(float)log((double)u);
  return -(float)log((double)t);
}

// Phase A: logits[b][n] = W2 . tanh(W1^T [curr_b; nodes_bn] + b1) + b2
__global__ __launch_bounds__(256) void k_logits(
    const float* __restrict__ nodes, const int* __restrict__ nn,
    const float* __restrict__ W1, const float* __restrict__ b1,
    const float* __restrict__ W2, const float* __restrict__ b2,
    float* __restrict__ logits) {
  const int lane = threadIdx.x & 63;
  const int gw = (blockIdx.x * 256 + threadIdx.x) >> 6;   // wave id = (b,n)
  const int b = gw >> 10, n = gw & (NDIM - 1);
  const int cn = nn[b];
  const float a = nodes[((size_t)b * NDIM + cn) * DDIM + lane];  // curr
  const float x = nodes[((size_t)b * NDIM + n) * DDIM + lane];
  float acc = b1[lane];
#pragma unroll 8
  for (int k = 0; k < 64; ++k)
    acc = fmaf(__shfl(a, k), W1[k * DDIM + lane], acc);
#pragma unroll 8
  for (int k = 0; k < 64; ++k)
    acc = fmaf(__shfl(x, k), W1[(64 + k) * DDIM + lane], acc);
  float p = tanhf(acc) * W2[lane];
  for (int off = 32; off; off >>= 1) p += __shfl_down(p, off);
  if (lane == 0) logits[b * NDIM + n] = p + b2[0];
}

// Phase B: pure hash compute. One block per active (b,r); writes 5 argmax
// columns to hitc[(b,r)][0..4] (stride 8). Inactive rows exit immediately.
__global__ __launch_bounds__(256) void k_hash(
    const float* __restrict__ w_in, const float* __restrict__ logits,
    const int* __restrict__ nn_arr, int* __restrict__ hitc, Keys keys) {
  const int b = blockIdx.x;    // 0..31
  const int r = blockIdx.y;    // 0..1023
  const int nn = nn_arr[b];
  if (r > nn) return;
  const int tid = threadIdx.x;

  __shared__ unsigned long long red[NEDGE][4];
  __shared__ int flg;
  if (tid == 0) flg = 0;
  __syncthreads();

  const size_t row = ((size_t)b * NDIM + r) * NDIM;
  const uint32_t pbase = (uint32_t)b * (NDIM * NDIM) + (uint32_t)r * NDIM;

  unsigned long long best[NEDGE];
#pragma unroll
  for (int e = 0; e < NEDGE; ++e) best[e] = 0ull;
  bool wnz = false;
  for (int c = tid; c <= nn; c += 256) {
    float w = w_in[row + c];
    if (r == nn && c < nn) w = logits[b * NDIM + c];
    wnz |= (w != 0.f);
    const uint32_t p = pbase + (uint32_t)c;
    const unsigned long long lo = (unsigned long long)(1024 - c); // tie -> smaller c
#pragma unroll
    for (int e = 0; e < NEDGE; ++e) {
      const uint32_t bits = tf_bits(keys.a[e], keys.b[e], p);
      const unsigned long long pk = ((unsigned long long)(bits >> 9) << 32) | lo;
      if (pk > best[e]) best[e] = pk;
    }
  }
  if (wnz) flg = 1;
#pragma unroll
  for (int e = 0; e < NEDGE; ++e) {
    unsigned long long v = best[e];
    for (int off = 32; off; off >>= 1) {
      unsigned long long o = __shfl_xor(v, off);
      if (o > v) v = o;
    }
    if ((tid & 63) == 0) red[e][tid >> 6] = v;
  }
  __syncthreads();

  if (flg) {  // block-uniform; only the patched logit row per batch
    unsigned long long fb[NEDGE];
#pragma unroll
    for (int e = 0; e < NEDGE; ++e) fb[e] = 0ull;
    for (int c = tid; c <= nn; c += 256) {
      float w = w_in[row + c];
      if (r == nn && c < nn) w = logits[b * NDIM + c];
      const uint32_t p = pbase + (uint32_t)c;
      const unsigned long long lo = (unsigned long long)(1024 - c);
#pragma unroll
      for (int e = 0; e < NEDGE; ++e) {
        const float pert = w + gumbel_bits(tf_bits(keys.a[e], keys.b[e], p));
        const uint32_t fu = __float_as_uint(pert);
        const uint32_t key = (fu & 0x80000000u) ? ~fu : (fu | 0x80000000u);
        const unsigned long long pk = ((unsigned long long)key << 32) | lo;
        if (pk > fb[e]) fb[e] = pk;
      }
    }
#pragma unroll
    for (int e = 0; e < NEDGE; ++e) {
      unsigned long long v = fb[e];
      for (int off = 32; off; off >>= 1) {
        unsigned long long o = __shfl_xor(v, off);
        if (o > v) v = o;
      }
      if ((tid & 63) == 0) red[e][tid >> 6] = v;
    }
  }
  __syncthreads();
  if (tid < NEDGE) {
    unsigned long long v = red[tid][0];
    for (int w = 1; w < 4; ++w) if (red[tid][w] > v) v = red[tid][w];
    hitc[(((b << 10) | r) << 3) + tid] = 1024 - (int)(v & 0xFFFFFFFFull);
  }
}

// Phase C: pure streaming. One block per (r,b): copy adj row (OR hits, zero
// diag) and weights row (patch logits) — 8KB in / 8KB out per block.
__global__ __launch_bounds__(256) void k_out(
    const float* __restrict__ adj_in, const float* __restrict__ w_in,
    const float* __restrict__ logits, const int* __restrict__ nn_arr,
    const int* __restrict__ hitc,
    float* __restrict__ adj_out, float* __restrict__ w_out) {
  const int r = blockIdx.x;    // 0..1023 (fastest: stream rows within batch)
  const int b = blockIdx.y;    // 0..31
  const int tid = threadIdx.x;
  const int nn = nn_arr[b];
  const size_t row = ((size_t)b * NDIM + r) * NDIM;

  // adjacency row
  float4 v = ((const float4*)(adj_in + row))[tid];
  float* vf = (float*)&v;
  int h0 = 1024, h1 = 1024, h2 = 1024, h3 = 1024, h4 = 1024;
  if (r <= nn) {
    const int* hp = hitc + (((b << 10) | r) << 3);
    h0 = hp[0]; h1 = hp[1]; h2 = hp[2]; h3 = hp[3]; h4 = hp[4];
  }
  const int c0 = tid * 4;
#pragma unroll
  for (int jx = 0; jx < 4; ++jx) {
    const int c = c0 + jx;
    float f = vf[jx];
    if (c == h0 || c == h1 || c == h2 || c == h3 || c == h4) f = 1.0f;
    if (c == r) f = 0.0f;
    vf[jx] = f;
  }
  ((float4*)(adj_out + row))[tid] = v;

  // weights row
  float4 wv = ((const float4*)(w_in + row))[tid];
  if (r == nn) {
    float* wf = (float*)&wv;
#pragma unroll
    for (int jx = 0; jx < 4; ++jx)
      if (c0 + jx < nn) wf[jx] = logits[b * NDIM + c0 + jx];
  }
  ((float4*)(w_out + row))[tid] = wv;
}

extern "C" void kernel_launch(void* const* d_in, const int* in_sizes, int n_in,
                              void* d_out, int out_size, void* d_ws, size_t ws_size,
                              hipStream_t stream) {
  (void)in_sizes; (void)n_in; (void)out_size; (void)ws_size;
  const float* nodes = (const float*)d_in[0];
  const float* adj   = (const float*)d_in[1];
  const float* wts   = (const float*)d_in[2];
  const int*   nn    = (const int*)d_in[3];
  const float* W1    = (const float*)d_in[5];
  const float* b1    = (const float*)d_in[6];
  const float* W2    = (const float*)d_in[7];
  const float* b2    = (const float*)d_in[8];

  float* adj_out = (float*)d_out;
  float* w_out   = adj_out + (size_t)BDIM * NDIM * NDIM;
  float* logits  = (float*)d_ws;                       // 128 KB
  int*   hitc    = (int*)((char*)d_ws + (size_t)BDIM * NDIM * 4);  // 1 MB

  // folded keys: k_i = threefry2x32(key=(0,42), data=(0,i))  [jax.random.fold_in]
  Keys keys;
  for (int i = 0; i < NEDGE; ++i) {
    uint32_t o0, o1;
    tf2x32(0u, 42u, 0u, (uint32_t)i, o0, o1);
    keys.a[i] = o0; keys.b[i] = o1;
  }

  k_logits<<<dim3(BDIM * NDIM / 4), 256, 0, stream>>>(nodes, nn, W1, b1, W2, b2, logits);
  k_hash  <<<dim3(BDIM, NDIM), 256, 0, stream>>>(wts, logits, nn, hitc, keys);
  k_out   <<<dim3(NDIM, BDIM), 256, 0, stream>>>(adj, wts, logits, nn, hitc, adj_out, w_out);
}

// Round 4
// 286.948 us; speedup vs baseline: 2.0477x; 2.0477x over previous
//
#include <hip/hip_runtime.h>
#include <hip/hip_bf16.h>
#include <cstdint>
#include <math.h>

#define NDIM 1024
#define BDIM 32
#define DDIM 64
#define NEDGE 5

struct Keys { uint32_t a[NEDGE]; uint32_t b[NEDGE]; };

// JAX Threefry-2x32, 20 rounds. Matches jax/_src/prng.py exactly.
#define TF_R(r) do { x0 += x1; x1 = (x1 << (r)) | (x1 >> (32 - (r))); x1 ^= x0; } while (0)
__host__ __device__ inline void tf2x32(uint32_t k0, uint32_t k1,
                                       uint32_t x0, uint32_t x1,
                                       uint32_t& o0, uint32_t& o1) {
  const uint32_t ks2 = k0 ^ k1 ^ 0x1BD11BDAu;
  x0 += k0; x1 += k1;
  TF_R(13); TF_R(15); TF_R(26); TF_R(6);
  x0 += k1; x1 += ks2 + 1u;
  TF_R(17); TF_R(29); TF_R(16); TF_R(24);
  x0 += ks2; x1 += k0 + 2u;
  TF_R(13); TF_R(15); TF_R(26); TF_R(6);
  x0 += k0; x1 += k1 + 3u;
  TF_R(17); TF_R(29); TF_R(16); TF_R(24);
  x0 += k1; x1 += ks2 + 4u;
  TF_R(13); TF_R(15); TF_R(26); TF_R(6);
  x0 += ks2; x1 += k0 + 5u;
  o0 = x0; o1 = x1;
}

// Partitionable threefry bits for linear position p: o0^o1 of tf(key; 0, p).
__device__ __forceinline__ uint32_t tf_bits(uint32_t k0, uint32_t k1, uint32_t p) {
  uint32_t o0, o1;
  tf2x32(k0, k1, 0u, p, o0, o1);
  return o0 ^ o1;
}

// bits -> uniform(1e-10,1) -> gumbel, replicating JAX's exact f32 op sequence
// (separate mul/add rounding — no FMA contraction), double-precision logs.
__device__ __forceinline__ float gumbel_bits(uint32_t bits) {
  float f = __uint_as_float((bits >> 9) | 0x3F800000u) - 1.0f;
  float u = fmaxf(1e-10f, __fadd_rn(__fmul_rn(f, 1.0f - 1e-10f), 1e-10f));
  float t = -(float)log((double)u);
  return -(float)log((double)t);
}

// Phase A: logits[b][n] = W2 . tanh(W1^T [curr_b; nodes_bn] + b1) + b2
__global__ __launch_bounds__(256) void k_logits(
    const float* __restrict__ nodes, const int* __restrict__ nn,
    const float* __restrict__ W1, const float* __restrict__ b1,
    const float* __restrict__ W2, const float* __restrict__ b2,
    float* __restrict__ logits) {
  const int lane = threadIdx.x & 63;
  const int gw = (blockIdx.x * 256 + threadIdx.x) >> 6;   // wave id = (b,n)
  const int b = gw >> 10, n = gw & (NDIM - 1);
  const int cn = nn[b];
  const float a = nodes[((size_t)b * NDIM + cn) * DDIM + lane];  // curr
  const float x = nodes[((size_t)b * NDIM + n) * DDIM + lane];
  float acc = b1[lane];
#pragma unroll 8
  for (int k = 0; k < 64; ++k)
    acc = fmaf(__shfl(a, k), W1[k * DDIM + lane], acc);
#pragma unroll 8
  for (int k = 0; k < 64; ++k)
    acc = fmaf(__shfl(x, k), W1[(64 + k) * DDIM + lane], acc);
  float p = tanhf(acc) * W2[lane];
  for (int off = 32; off; off >>= 1) p += __shfl_down(p, off);
  if (lane == 0) logits[b * NDIM + n] = p + b2[0];
}

// Fused phase: one WAVE per (b,r) row. Hash-argmax (no LDS, no barriers),
// then stream the adjacency row (OR hits, zero diag) and weights row
// (patch logits) — memory hides under the neighboring waves' VALU work.
__global__ __launch_bounds__(256) void k_main(
    const float* __restrict__ adj_in, const float* __restrict__ w_in,
    const float* __restrict__ logits, const int* __restrict__ nn_arr,
    float* __restrict__ adj_out, float* __restrict__ w_out, Keys keys) {
  const int tid = threadIdx.x;
  const int lane = tid & 63;
  const int gw = (blockIdx.x << 2) | (tid >> 6);   // wave id = row id
  const int b = gw >> 10;
  const int r = gw & (NDIM - 1);
  const int nn = nn_arr[b];
  const size_t row = (size_t)gw << 10;

  int bc[NEDGE];
#pragma unroll
  for (int e = 0; e < NEDGE; ++e) bc[e] = NDIM;   // sentinel: no hit

  if (r <= nn) {   // wave-uniform branch
    int bv[NEDGE], bcl[NEDGE];
#pragma unroll
    for (int e = 0; e < NEDGE; ++e) { bv[e] = -1; bcl[e] = NDIM; }
    bool wnz = false;
    for (int c = lane; c <= nn; c += 64) {
      float w = w_in[row + c];
      if (r == nn && c < nn) w = logits[(b << 10) + c];
      wnz |= (w != 0.f);
      const uint32_t p = (uint32_t)row + (uint32_t)c;
#pragma unroll
      for (int e = 0; e < NEDGE; ++e) {
        // gumbel monotone in bits>>9; per-lane c ascending -> strict '>'
        // keeps smallest c per lane automatically.
        const int v = (int)(tf_bits(keys.a[e], keys.b[e], p) >> 9);
        if (v > bv[e]) { bv[e] = v; bcl[e] = c; }
      }
    }
    if (__ballot(wnz)) {
      // float fallback: only rows with nonzero weights (patched logit row)
      uint32_t fk[NEDGE]; int fc[NEDGE];
#pragma unroll
      for (int e = 0; e < NEDGE; ++e) { fk[e] = 0u; fc[e] = NDIM; }
      for (int c = lane; c <= nn; c += 64) {
        float w = w_in[row + c];
        if (r == nn && c < nn) w = logits[(b << 10) + c];
        const uint32_t p = (uint32_t)row + (uint32_t)c;
#pragma unroll
        for (int e = 0; e < NEDGE; ++e) {
          const float pert = w + gumbel_bits(tf_bits(keys.a[e], keys.b[e], p));
          const uint32_t fu = __float_as_uint(pert);
          const uint32_t key = (fu & 0x80000000u) ? ~fu : (fu | 0x80000000u);
          if (key > fk[e]) { fk[e] = key; fc[e] = c; }
        }
      }
#pragma unroll
      for (int e = 0; e < NEDGE; ++e) {
        uint32_t k = fk[e]; int c = fc[e];
        for (int off = 32; off; off >>= 1) {
          const uint32_t ko = __shfl_xor(k, off);
          const int co = __shfl_xor(c, off);
          if (ko > k || (ko == k && co < c)) { k = ko; c = co; }
        }
        bc[e] = c;   // butterfly: all lanes hold the result
      }
    } else {
#pragma unroll
      for (int e = 0; e < NEDGE; ++e) {
        int v = bv[e]; int c = bcl[e];
        for (int off = 32; off; off >>= 1) {
          const int vo = __shfl_xor(v, off);
          const int co = __shfl_xor(c, off);
          if (vo > v || (vo == v && co < c)) { v = vo; c = co; }
        }
        bc[e] = c;
      }
    }
  }

  // Streaming epilogue: 4 float4 per lane per row, lane-coalesced.
  const float4* a4 = (const float4*)(adj_in + row);
  const float4* w4 = (const float4*)(w_in + row);
  float4* ao4 = (float4*)(adj_out + row);
  float4* wo4 = (float4*)(w_out + row);
  const bool patch = (r == nn);
#pragma unroll
  for (int k = 0; k < 4; ++k) {
    const int idx = (k << 6) | lane;
    float4 v = a4[idx];
    float4 wv = w4[idx];
    float* vf = (float*)&v;
    float* wf = (float*)&wv;
    const int c0 = idx << 2;
#pragma unroll
    for (int jx = 0; jx < 4; ++jx) {
      const int c = c0 + jx;
      float f = vf[jx];
      if (c == bc[0] || c == bc[1] || c == bc[2] || c == bc[3] || c == bc[4])
        f = 1.0f;
      if (c == r) f = 0.0f;
      vf[jx] = f;
      if (patch && c < nn) wf[jx] = logits[(b << 10) + c];
    }
    ao4[idx] = v;
    wo4[idx] = wv;
  }
}

extern "C" void kernel_launch(void* const* d_in, const int* in_sizes, int n_in,
                              void* d_out, int out_size, void* d_ws, size_t ws_size,
                              hipStream_t stream) {
  (void)in_sizes; (void)n_in; (void)out_size; (void)ws_size;
  const float* nodes = (const float*)d_in[0];
  const float* adj   = (const float*)d_in[1];
  const float* wts   = (const float*)d_in[2];
  const int*   nn    = (const int*)d_in[3];
  const float* W1    = (const float*)d_in[5];
  const float* b1    = (const float*)d_in[6];
  const float* W2    = (const float*)d_in[7];
  const float* b2    = (const float*)d_in[8];

  float* adj_out = (float*)d_out;
  float* w_out   = adj_out + (size_t)BDIM * NDIM * NDIM;
  float* logits  = (float*)d_ws;  // 32*1024 floats = 128 KB

  // folded keys: k_i = threefry2x32(key=(0,42), data=(0,i))  [jax.random.fold_in]
  Keys keys;
  for (int i = 0; i < NEDGE; ++i) {
    uint32_t o0, o1;
    tf2x32(0u, 42u, 0u, (uint32_t)i, o0, o1);
    keys.a[i] = o0; keys.b[i] = o1;
  }

  k_logits<<<dim3(BDIM * NDIM / 4), 256, 0, stream>>>(nodes, nn, W1, b1, W2, b2, logits);
  k_main  <<<dim3(BDIM * NDIM / 4), 256, 0, stream>>>(adj, wts, logits, nn, adj_out, w_out, keys);
}